// Round 17
// baseline (921.207 us; speedup 1.0000x reference)
//
#include <hip/hip_runtime.h>

typedef __bf16 bf16;
typedef __bf16 bf16x4 __attribute__((ext_vector_type(4)));
typedef __bf16 bf16x8 __attribute__((ext_vector_type(8)));
typedef float f32x4 __attribute__((ext_vector_type(4)));
typedef float f32x16 __attribute__((ext_vector_type(16)));
typedef int i32x2 __attribute__((ext_vector_type(2)));
typedef int i32x4 __attribute__((ext_vector_type(4)));
typedef unsigned int u32;

#define DIMC 384
#define NHEADS 12
#define NTOK 49
#define NWINB 4096
#define MROWS (NWINB*NTOK)   // 200704

#define MFMA32(A,B,C) __builtin_amdgcn_mfma_f32_32x32x16_bf16(A,B,C,0,0,0)

// async global->LDS, 16B per lane; LDS dest is wave-uniform base + lane*16.
// RULES (learned r10-r12, r15): (1) static __shared__ staging only; (2) never
// reuse the staging region for ds_write traffic later in the kernel; (3) manual
// counted vmcnt is only valid when EVERY in-loop VMEM op is explicitly ordered
// (builtin gload_lds or asm volatile loads) — no compiler-scheduled loads in
// the counted window; (4) rule #18: sched_barrier(0) after an inline-asm wait
// that guards register-only MFMA inputs.
#define GLOAD16(gsrc, lbase) \
  __builtin_amdgcn_global_load_lds( \
      (const __attribute__((address_space(1))) u32*)(gsrc), \
      (__attribute__((address_space(3))) u32*)(lbase), 16, 0, 0)

// explicit 16B global load into VGPRs, FIFO-ordered vs asm volatile waitcnts
#define BLOADX4(dst, ptr) \
  asm volatile("global_load_dwordx4 %0, %1, off" : "=v"(dst) : "v"(ptr))

// ---------------- convert f32 -> bf16 (vectorized) ----------------
__global__ __launch_bounds__(256) void k_convert(const float4* __restrict__ in,
                                                 bf16x4* __restrict__ out, int n4) {
  int stride = gridDim.x * blockDim.x;
  for (int i = blockIdx.x * blockDim.x + threadIdx.x; i < n4; i += stride) {
    float4 v = in[i];
    bf16x4 o;
    o[0] = (bf16)v.x; o[1] = (bf16)v.y; o[2] = (bf16)v.z; o[3] = (bf16)v.w;
    out[i] = o;
  }
}

// ---------------- combined transposed bias+mask table (r8/r9-proven) ----------------
// bmT[(h*64+w)][key*49+q] = table[rel[q*49+key]*12+h] + mask[(w*49+q)*49+key]
__global__ __launch_bounds__(256) void k_bm(const float* __restrict__ table,
                                            const int* __restrict__ rel,
                                            const float* __restrict__ mask,
                                            float* __restrict__ outp) {
  int i = blockIdx.x * 256 + threadIdx.x;
  if (i < NHEADS * 64 * NTOK * NTOK) {
    int hw = i / 2401, r2 = i - hw * 2401;
    int h = hw >> 6, w = hw & 63;
    int key = r2 / NTOK, q = r2 - key * NTOK;
    outp[i] = table[rel[q * NTOK + key] * NHEADS + h] + mask[(w * NTOK + q) * NTOK + key];
  }
}

// ---------------- GEMM: C = A(M,K) * Bw(N,K)^T, bf16 in, f32 acc ----------------
// BM=128 x BN=128 x BK=64. A: double-buffered 32KB LDS via global_load_lds
// (XOR-swizzled, r13-green schedule). B: fragments loaded DIRECTLY from global
// via asm-volatile global_load_dwordx4 (weights L2-resident, sector-optimal) —
// halves per-MFMA LDS read traffic (the measured MfmaUtil wall) and doubles
// blocks/CU. All in-loop VMEM ops explicitly ordered -> counted vmcnt sound:
//   per step: 8 B-asm + 4 A-glds issued; vmcnt(12) drains A(t);
//   after barrier vmcnt(4) drains B(t) (A(t+1) stays in flight);
//   sched_barrier(0) pins MFMA below the wait (rule #18).
// MODE 0: QKV (N=1152), scatter q/k/v packed (p,49,32).  MODE 1: proj -> f32+bias.
template <int MODE>
__global__ __launch_bounds__(256) void k_gemm(const bf16* __restrict__ A,
                                              const bf16* __restrict__ Bw,
                                              const float* __restrict__ bias,
                                              bf16* __restrict__ oQ, bf16* __restrict__ oK,
                                              bf16* __restrict__ oV, float* __restrict__ oP) {
  __shared__ __align__(16) bf16 lA[2][128 * 64];
  const int t = threadIdx.x;
  const int l = t & 63;
  const int wv = t >> 6;
  const int wr = wv >> 1, wc = wv & 1;   // 2x2 waves, 64x64 each

  // ---- bijective XCD-chunk remap (nwg % 8 == 0 for both modes) ----
  const u32 NXB = MODE == 0 ? 9 : 3;                 // N-blocks
  const u32 nwg = NXB * (MROWS / 128);
  u32 lin = blockIdx.y * gridDim.x + blockIdx.x;     // dispatch-linear (x fastest)
  u32 logical = (lin & 7) * (nwg >> 3) + (lin >> 3); // XCD gets contiguous chunk
  const int n0 = (int)(logical % NXB) * 128;
  const int m0 = (int)(logical / NXB) * 128;

  const int lr = l & 15, lg = l >> 4;

  // staging geometry: lane's linear tile byte offset = wv*4096 + i*1024 + l*16
  const int srow = wv * 32 + (l >> 3);           // + i*8 per issue
  const int scolb = (l & 7) * 16;                // byte col within 128B row

  f32x4 acc[4][4] = {};

  // per-lane pre-swizzled source column (elements) for each of the 4 issues
  int scolA[4];
#pragma unroll
  for (int i = 0; i < 4; ++i) {
    int row = srow + i * 8;
    scolA[i] = (scolb ^ ((row & 7) << 4)) >> 1;
  }

  // B fragment base: row = n0 + wc*64 + f*16 + lr, col walks k (lg*8 elems in)
  const bf16* bwbase = Bw + (size_t)(n0 + wc * 64 + lr) * DIMC + lg * 8;

#define STAGEA(BUF, K0)                                                           \
  {                                                                               \
    _Pragma("unroll") for (int i = 0; i < 4; ++i) {                               \
      int row = srow + i * 8;                                                     \
      GLOAD16(&A[(size_t)(m0 + row) * DIMC + (K0) + scolA[i]],                    \
              &lA[BUF][wv * 2048 + i * 512]);                                     \
    }                                                                             \
  }

  STAGEA(0, 0);                     // prologue: A tile 0 in flight (4 glds)

#pragma unroll
  for (int tt = 0; tt < 6; ++tt) {  // K = 384 = 6 x 64, fully unrolled
    const int cur = tt & 1;
    if (tt > 0) __builtin_amdgcn_s_barrier();      // compute(tt-1) done -> buf reuse safe

    // B(tt) fragments via explicit asm loads (8 x 16B) — enter the FIFO here
    union { i32x4 r; bf16x8 v; } braw[2][4];
#pragma unroll
    for (int kk = 0; kk < 2; ++kk)
#pragma unroll
      for (int f = 0; f < 4; ++f)
        BLOADX4(braw[kk][f].r, &bwbase[(size_t)f * 16 * DIMC + tt * 64 + kk * 32]);

    if (tt < 5) {
      STAGEA(cur ^ 1, (tt + 1) * 64);              // prefetch next A tile (4 glds)
      asm volatile("s_waitcnt vmcnt(12)" ::: "memory");  // drain A(tt) only
    } else {
      asm volatile("s_waitcnt vmcnt(8)" ::: "memory");   // drain A(5); 8 B remain
    }
    __builtin_amdgcn_s_barrier();                  // all waves' A tile-tt visible

#pragma unroll
    for (int kk = 0; kk < 2; ++kk) {
      bf16x8 af[4];
#pragma unroll
      for (int f = 0; f < 4; ++f) {
        int row = wr * 64 + f * 16 + lr;
        int cb = (kk * 32 + lg * 8) * 2;
        af[f] = *reinterpret_cast<const bf16x8*>(
            &lA[cur][row * 64 + ((cb ^ ((row & 7) << 4)) >> 1)]);
      }
      if (kk == 0) {
        if (tt < 5) asm volatile("s_waitcnt vmcnt(4)" ::: "memory");  // B(tt) ready
        else        asm volatile("s_waitcnt vmcnt(0)" ::: "memory");
        __builtin_amdgcn_sched_barrier(0);         // rule #18: MFMA stays below
      }
#pragma unroll
      for (int fm = 0; fm < 4; ++fm)
#pragma unroll
        for (int fn = 0; fn < 4; ++fn)
          acc[fm][fn] = __builtin_amdgcn_mfma_f32_16x16x32_bf16(af[fm], braw[kk][fn].v, acc[fm][fn], 0, 0, 0);
    }
  }
#undef STAGEA

  // epilogue: C/D frag mapping col = lane&15, row = (lane>>4)*4 + r  [m89-verified]
#pragma unroll
  for (int fm = 0; fm < 4; ++fm) {
#pragma unroll
    for (int fn = 0; fn < 4; ++fn) {
      int c = n0 + wc * 64 + fn * 16 + lr;
      float bc = bias[c];
#pragma unroll
      for (int r = 0; r < 4; ++r) {
        int m = m0 + wr * 64 + fm * 16 + lg * 4 + r;
        float v = acc[fm][fn][r] + bc;
        if (MODE == 0) {
          int b = m / 49, n = m - b * 49;
          int which = c / 384;
          int rem = c - which * 384;
          int h = rem >> 5, d = rem & 31;
          bf16* dst = which == 0 ? oQ : (which == 1 ? oK : oV);
          dst[((b * 12 + h) * 49 + n) * 32 + d] = (bf16)v;
        } else {
          oP[m * 384 + c] = v;
        }
      }
    }
  }
}

// ---------------- fused window attention: one wave per (b,h), 32x32 MFMA ----------------
// (r16 green, unchanged) Swapped QK^T, lane-local no-max softmax (|score| <= ~6,
// f32-safe; softmax shift-invariant), P in registers via cvt-pack +
// permlane32_swap, V staged transposed in LDS, setprio around MFMA.
__global__ __launch_bounds__(256, 4) void k_attn(const bf16* __restrict__ Q,
                                                 const bf16* __restrict__ K,
                                                 const bf16* __restrict__ V,
                                                 const float* __restrict__ bmT,
                                                 bf16* __restrict__ H) {
  __shared__ __align__(16) bf16 Vl[4][32 * 72];
  const int t = threadIdx.x, l = t & 63, wv = t >> 6;
  const int p = blockIdx.x * 4 + wv;   // b*12 + h
  const int b = p / 12, h = p - b * 12;
  const int w = b & 63;
  const size_t base = (size_t)p * (49 * 32);
  const int c = l & 31, b5 = l >> 5;
  bf16* vl = Vl[wv];

  // zero pad keys 48..63 (key 48 re-written by staging below)
  {
    bf16x4 z = {};
    for (int i = l; i < 128; i += 64) {
      int d = i >> 2, kq = 48 + (i & 3) * 4;
      *reinterpret_cast<bf16x4*>(&vl[d * 72 + kq]) = z;
    }
  }
  // stage V transposed: vl[d*72 + key] = V[key*32 + d]
  for (int i = l; i < 392; i += 64) {
    int key = i >> 3, dc = (i & 7) * 4;
    bf16x4 vv = *reinterpret_cast<const bf16x4*>(&V[base + key * 32 + dc]);
#pragma unroll
    for (int j = 0; j < 4; ++j) vl[(dc + j) * 72 + key] = vv[j];
  }

  // K/Q fragments: lane holds X[row = f*32 + c][d = kd*16 + b5*8 + j], rows clamped
  bf16x8 kf[2][2], qf[2][2];
#pragma unroll
  for (int f = 0; f < 2; ++f) {
    int row = f * 32 + c; if (row > 48) row = 48;
#pragma unroll
    for (int kd = 0; kd < 2; ++kd) {
      kf[f][kd] = *reinterpret_cast<const bf16x8*>(&K[base + row * 32 + kd * 16 + b5 * 8]);
      qf[f][kd] = *reinterpret_cast<const bf16x8*>(&Q[base + row * 32 + kd * 16 + b5 * 8]);
    }
  }

  const float scale = 0.17677669529663689f;   // 32^-0.5
  const float* bm = bmT + ((size_t)h * 64 + w) * 2401;

#pragma unroll
  for (int fn = 0; fn < 2; ++fn) {
    // swapped QK^T: S[key][q], C layout col=lane&31=q, row=(r&3)+8*(r>>2)+4*b5=key
    f32x16 s0 = {}, s1 = {};
    __builtin_amdgcn_s_setprio(1);
    s0 = MFMA32(kf[0][0], qf[fn][0], s0);
    s0 = MFMA32(kf[0][1], qf[fn][1], s0);
    s1 = MFMA32(kf[1][0], qf[fn][0], s1);
    s1 = MFMA32(kf[1][1], qf[fn][1], s1);
    __builtin_amdgcn_s_setprio(0);

    int q = fn * 32 + c;
    int qc = q > 48 ? 48 : q;

    // softmax without max-subtract: e = exp(score); |score| <= ~6 in f32-safe range
    float vals[32];
    float sum = 0.f;
#pragma unroll
    for (int fm = 0; fm < 2; ++fm) {
#pragma unroll
      for (int r = 0; r < 16; ++r) {
        int key = fm * 32 + (r & 3) + 8 * (r >> 2) + 4 * b5;
        float sv = fm ? s1[r] : s0[r];
        float e;
        if (key < 49) {
          e = __expf(fmaf(sv, scale, bm[key * 49 + qc]));
        } else {
          e = 0.f;
        }
        vals[fm * 16 + r] = e;
        sum += e;
      }
    }
    sum += __shfl_xor(sum, 32);
    float inv = 1.f / sum;

    // PV: build P A-frags in-register (cvt pack + permlane32_swap), MFMA with LDS V
    f32x16 o = {};
#pragma unroll
    for (int kk = 0; kk < 4; ++kk) {
      int ib = (kk >> 1) * 16 + 8 * (kk & 1);
      union { bf16 hh[2]; u32 u; } cv;
      u32 A0, A1, B0, B1;
      cv.hh[0] = (bf16)(vals[ib + 0] * inv); cv.hh[1] = (bf16)(vals[ib + 1] * inv); A0 = cv.u;
      cv.hh[0] = (bf16)(vals[ib + 2] * inv); cv.hh[1] = (bf16)(vals[ib + 3] * inv); A1 = cv.u;
      cv.hh[0] = (bf16)(vals[ib + 4] * inv); cv.hh[1] = (bf16)(vals[ib + 5] * inv); B0 = cv.u;
      cv.hh[0] = (bf16)(vals[ib + 6] * inv); cv.hh[1] = (bf16)(vals[ib + 7] * inv); B1 = cv.u;
      i32x2 sw0 = __builtin_amdgcn_permlane32_swap((int)A0, (int)B0, false, false);
      i32x2 sw1 = __builtin_amdgcn_permlane32_swap((int)A1, (int)B1, false, false);
      union { u32 d[4]; bf16x8 v8; } pa;
      pa.d[0] = (u32)sw0[0]; pa.d[1] = (u32)sw1[0];
      pa.d[2] = (u32)sw0[1]; pa.d[3] = (u32)sw1[1];
      bf16x8 vf = *reinterpret_cast<const bf16x8*>(&vl[c * 72 + kk * 16 + b5 * 8]);
      __builtin_amdgcn_s_setprio(1);
      o = MFMA32(pa.v8, vf, o);
      __builtin_amdgcn_s_setprio(0);
    }

    // store O: row q = fn*32 + (r&3)+8*(r>>2)+4*b5, col d = c
#pragma unroll
    for (int r = 0; r < 16; ++r) {
      int qrow = fn * 32 + (r & 3) + 8 * (r >> 2) + 4 * b5;
      if (qrow < 49)
        H[((size_t)b * 49 + qrow) * 384 + h * 32 + c] = (bf16)o[r];
    }
  }
}

extern "C" void kernel_launch(void* const* d_in, const int* in_sizes, int n_in,
                              void* d_out, int out_size, void* d_ws, size_t ws_size,
                              hipStream_t stream) {
  const float* x     = (const float*)d_in[0];
  const float* mask  = (const float*)d_in[1];
  const float* qkvw  = (const float*)d_in[2];
  const float* qkvb  = (const float*)d_in[3];
  const float* btab  = (const float*)d_in[4];
  const float* projw = (const float*)d_in[5];
  const float* projb = (const float*)d_in[6];
  const int*   rel   = (const int*)d_in[7];
  float* out = (float*)d_out;

  const size_t NB  = 154140672;   // one [200704][384] bf16 buffer (bytes)
  char* ws = (char*)d_ws;
  // ws layout: xb/h [0,NB) | v [NB,2NB) | wqkv (+884736) | wproj (+294912) | bmT (7.4MB)
  bf16*  xb    = (bf16*)ws;
  bf16*  vb    = (bf16*)(ws + NB);
  bf16*  wqkv  = (bf16*)(ws + 2 * NB);
  bf16*  wproj = (bf16*)(ws + 2 * NB + 884736);
  float* bmT   = (float*)(ws + 2 * NB + 884736 + 294912);
  // q,k packed (p,49,32) live in d_out scratch (2*154,140,672 B exactly)
  bf16* qb = (bf16*)d_out;
  bf16* kb = qb + NB / 2;

  k_convert<<<2048, 256, 0, stream>>>((const float4*)x, (bf16x4*)xb, (int)(NB / 8));
  k_convert<<<432, 256, 0, stream>>>((const float4*)qkvw, (bf16x4*)wqkv, 3 * DIMC * DIMC / 4);
  k_convert<<<144, 256, 0, stream>>>((const float4*)projw, (bf16x4*)wproj, DIMC * DIMC / 4);
  k_bm<<<(NHEADS * 64 * NTOK * NTOK + 255) / 256, 256, 0, stream>>>(btab, rel, mask, bmT);

  k_gemm<0><<<dim3(9, MROWS / 128), 256, 0, stream>>>(xb, wqkv, qkvb, qb, kb, vb, nullptr);
  k_attn<<<(NWINB * NHEADS) / 4, 256, 0, stream>>>(qb, kb, vb, bmT, xb);
  k_gemm<1><<<dim3(3, MROWS / 128), 256, 0, stream>>>(xb, wproj, projb, nullptr, nullptr, nullptr, out);
}

// Round 18
// 758.104 us; speedup vs baseline: 1.2151x; 1.2151x over previous
//
#include <hip/hip_runtime.h>

typedef __bf16 bf16;
typedef __bf16 bf16x4 __attribute__((ext_vector_type(4)));
typedef __bf16 bf16x8 __attribute__((ext_vector_type(8)));
typedef float f32x4 __attribute__((ext_vector_type(4)));
typedef float f32x16 __attribute__((ext_vector_type(16)));
typedef int i32x2 __attribute__((ext_vector_type(2)));
typedef unsigned int u32;

#define DIMC 384
#define NHEADS 12
#define NTOK 49
#define NWINB 4096
#define MROWS (NWINB*NTOK)   // 200704

#define MFMA32(A,B,C) __builtin_amdgcn_mfma_f32_32x32x16_bf16(A,B,C,0,0,0)

// async global->LDS, 16B per lane; LDS dest is wave-uniform base + lane*16.
// RULES (learned r10-r12, r15, r17): (1) static __shared__ staging only;
// (2) never reuse the staging region for ds_write traffic later in the kernel;
// (3) manual counted vmcnt only when EVERY in-loop VMEM op is explicitly
// ordered; (4) B-operand must be LDS-staged a full step ahead — in-loop L2
// loads enter the per-step critical path (r17: +137us).
#define GLOAD16(gsrc, lbase) \
  __builtin_amdgcn_global_load_lds( \
      (const __attribute__((address_space(1))) u32*)(gsrc), \
      (__attribute__((address_space(3))) u32*)(lbase), 16, 0, 0)

// ---------------- convert f32 -> bf16 (vectorized, x only) ----------------
__global__ __launch_bounds__(256) void k_convert(const float4* __restrict__ in,
                                                 bf16x4* __restrict__ out, int n4) {
  int stride = gridDim.x * blockDim.x;
  for (int i = blockIdx.x * blockDim.x + threadIdx.x; i < n4; i += stride) {
    float4 v = in[i];
    bf16x4 o;
    o[0] = (bf16)v.x; o[1] = (bf16)v.y; o[2] = (bf16)v.z; o[3] = (bf16)v.w;
    out[i] = o;
  }
}

// ---------------- fused prep: wqkv convert + wproj convert + bm table ----------------
// item i in [0, 110592): wqkv f4 convert; [110592, 147456): wproj f4 convert;
// [147456, 1991424): bmT[(h*64+w)][key*49+q] = table[rel[q*49+key]*12+h]
//                                             + mask[(w*49+q)*49+key]
__global__ __launch_bounds__(256) void k_prep(const float* __restrict__ qkvw,
                                              const float* __restrict__ projw,
                                              const float* __restrict__ table,
                                              const int* __restrict__ rel,
                                              const float* __restrict__ mask,
                                              bf16* __restrict__ wqkv,
                                              bf16* __restrict__ wproj,
                                              float* __restrict__ bmT) {
  int i = blockIdx.x * 256 + threadIdx.x;   // grid exactly covers 1,991,424 items
  if (i < 110592) {
    float4 v = reinterpret_cast<const float4*>(qkvw)[i];
    bf16x4 o;
    o[0] = (bf16)v.x; o[1] = (bf16)v.y; o[2] = (bf16)v.z; o[3] = (bf16)v.w;
    reinterpret_cast<bf16x4*>(wqkv)[i] = o;
  } else if (i < 147456) {
    int j = i - 110592;
    float4 v = reinterpret_cast<const float4*>(projw)[j];
    bf16x4 o;
    o[0] = (bf16)v.x; o[1] = (bf16)v.y; o[2] = (bf16)v.z; o[3] = (bf16)v.w;
    reinterpret_cast<bf16x4*>(wproj)[j] = o;
  } else {
    int j = i - 147456;                     // 0 .. 12*64*2401-1
    int hw = j / 2401, r2 = j - hw * 2401;
    int h = hw >> 6, w = hw & 63;
    int key = r2 / NTOK, q = r2 - key * NTOK;
    bmT[j] = table[rel[q * NTOK + key] * NHEADS + h] + mask[(w * NTOK + q) * NTOK + key];
  }
}

// ---------------- GEMM: C = A(M,K) * Bw(N,K)^T, bf16 in, f32 acc ----------------
// (r16 green, byte-identical) BM=128 x BN=128 x BK=64, double-buffered,
// counted vmcnt(8), raw s_barriers, XOR-swizzled static LDS via pre-swizzled
// global source, XCD-chunk remap (contiguous M-panels per XCD). No setprio
// (r13/r14 A/B: costs ~9us on this lockstep GEMM).
// MODE 0: QKV (N=1152), scatter q/k/v packed (p,49,32).  MODE 1: proj -> f32+bias.
template <int MODE>
__global__ __launch_bounds__(256) void k_gemm(const bf16* __restrict__ A,
                                              const bf16* __restrict__ Bw,
                                              const float* __restrict__ bias,
                                              bf16* __restrict__ oQ, bf16* __restrict__ oK,
                                              bf16* __restrict__ oV, float* __restrict__ oP) {
  __shared__ __align__(16) bf16 lA[2][128 * 64];
  __shared__ __align__(16) bf16 lB[2][128 * 64];
  const int t = threadIdx.x;
  const int l = t & 63;
  const int wv = t >> 6;
  const int wr = wv >> 1, wc = wv & 1;   // 2x2 waves, 64x64 each

  // ---- bijective XCD-chunk remap (nwg % 8 == 0 for both modes) ----
  const u32 NXB = MODE == 0 ? 9 : 3;                 // N-blocks
  const u32 nwg = NXB * (MROWS / 128);
  u32 lin = blockIdx.y * gridDim.x + blockIdx.x;     // dispatch-linear (x fastest)
  u32 logical = (lin & 7) * (nwg >> 3) + (lin >> 3); // XCD gets contiguous chunk
  const int n0 = (int)(logical % NXB) * 128;
  const int m0 = (int)(logical / NXB) * 128;

  const int lr = l & 15, lg = l >> 4;

  // staging geometry: lane's linear tile byte offset = wv*4096 + i*1024 + l*16
  const int srow = wv * 32 + (l >> 3);           // + i*8 per issue
  const int scolb = (l & 7) * 16;                // byte col within 128B row

  f32x4 acc[4][4] = {};

  // per-lane pre-swizzled source column (elements) for each of the 4 issues
  int scolA[4];
#pragma unroll
  for (int i = 0; i < 4; ++i) {
    int row = srow + i * 8;
    scolA[i] = (scolb ^ ((row & 7) << 4)) >> 1;
  }

#define STAGE(BUF, K0)                                                            \
  {                                                                               \
    _Pragma("unroll") for (int i = 0; i < 4; ++i) {                               \
      int row = srow + i * 8;                                                     \
      GLOAD16(&A[(size_t)(m0 + row) * DIMC + (K0) + scolA[i]],                    \
              &lA[BUF][wv * 2048 + i * 512]);                                     \
      GLOAD16(&Bw[(size_t)(n0 + row) * DIMC + (K0) + scolA[i]],                   \
              &lB[BUF][wv * 2048 + i * 512]);                                     \
    }                                                                             \
  }

  STAGE(0, 0);                      // prologue: tile 0 in flight

#pragma unroll
  for (int tt = 0; tt < 6; ++tt) {  // K = 384 = 6 x 64, fully unrolled
    const int cur = tt & 1;
    if (tt > 0) __builtin_amdgcn_s_barrier();      // compute(tt-1) done -> buf reuse safe
    if (tt < 5) {
      STAGE(cur ^ 1, (tt + 1) * 64);               // prefetch next tile
      asm volatile("s_waitcnt vmcnt(8)" ::: "memory");   // wait ONLY tile-tt's 8 loads
    } else {
      asm volatile("s_waitcnt vmcnt(0)" ::: "memory");
    }
    __builtin_amdgcn_s_barrier();                  // all waves' tile-tt data visible

#pragma unroll
    for (int kk = 0; kk < 64; kk += 32) {
      bf16x8 af[4], bfv[4];
#pragma unroll
      for (int f = 0; f < 4; ++f) {
        int row = wr * 64 + f * 16 + lr;
        int cb = (kk + lg * 8) * 2;
        af[f] = *reinterpret_cast<const bf16x8*>(
            &lA[cur][row * 64 + ((cb ^ ((row & 7) << 4)) >> 1)]);
      }
#pragma unroll
      for (int f = 0; f < 4; ++f) {
        int row = wc * 64 + f * 16 + lr;
        int cb = (kk + lg * 8) * 2;
        bfv[f] = *reinterpret_cast<const bf16x8*>(
            &lB[cur][row * 64 + ((cb ^ ((row & 7) << 4)) >> 1)]);
      }
#pragma unroll
      for (int fm = 0; fm < 4; ++fm)
#pragma unroll
        for (int fn = 0; fn < 4; ++fn)
          acc[fm][fn] = __builtin_amdgcn_mfma_f32_16x16x32_bf16(af[fm], bfv[fn], acc[fm][fn], 0, 0, 0);
    }
  }
#undef STAGE

  // epilogue: C/D frag mapping col = lane&15, row = (lane>>4)*4 + r  [m89-verified]
#pragma unroll
  for (int fm = 0; fm < 4; ++fm) {
#pragma unroll
    for (int fn = 0; fn < 4; ++fn) {
      int c = n0 + wc * 64 + fn * 16 + lr;
      float bc = bias[c];
#pragma unroll
      for (int r = 0; r < 4; ++r) {
        int m = m0 + wr * 64 + fm * 16 + lg * 4 + r;
        float v = acc[fm][fn][r] + bc;
        if (MODE == 0) {
          int b = m / 49, n = m - b * 49;
          int which = c / 384;
          int rem = c - which * 384;
          int h = rem >> 5, d = rem & 31;
          bf16* dst = which == 0 ? oQ : (which == 1 ? oK : oV);
          dst[((b * 12 + h) * 49 + n) * 32 + d] = (bf16)v;
        } else {
          oP[m * 384 + c] = v;
        }
      }
    }
  }
}

// ---------------- fused window attention: one wave per (b,h), 32x32 MFMA ----------------
// (r16 green, unchanged) Swapped QK^T, lane-local no-max softmax (|score| <= ~6,
// f32-safe; softmax shift-invariant), P in registers via cvt-pack +
// permlane32_swap, V staged transposed in LDS, setprio around MFMA.
__global__ __launch_bounds__(256, 4) void k_attn(const bf16* __restrict__ Q,
                                                 const bf16* __restrict__ K,
                                                 const bf16* __restrict__ V,
                                                 const float* __restrict__ bmT,
                                                 bf16* __restrict__ H) {
  __shared__ __align__(16) bf16 Vl[4][32 * 72];
  const int t = threadIdx.x, l = t & 63, wv = t >> 6;
  const int p = blockIdx.x * 4 + wv;   // b*12 + h
  const int b = p / 12, h = p - b * 12;
  const int w = b & 63;
  const size_t base = (size_t)p * (49 * 32);
  const int c = l & 31, b5 = l >> 5;
  bf16* vl = Vl[wv];

  // zero pad keys 48..63 (key 48 re-written by staging below)
  {
    bf16x4 z = {};
    for (int i = l; i < 128; i += 64) {
      int d = i >> 2, kq = 48 + (i & 3) * 4;
      *reinterpret_cast<bf16x4*>(&vl[d * 72 + kq]) = z;
    }
  }
  // stage V transposed: vl[d*72 + key] = V[key*32 + d]
  for (int i = l; i < 392; i += 64) {
    int key = i >> 3, dc = (i & 7) * 4;
    bf16x4 vv = *reinterpret_cast<const bf16x4*>(&V[base + key * 32 + dc]);
#pragma unroll
    for (int j = 0; j < 4; ++j) vl[(dc + j) * 72 + key] = vv[j];
  }

  // K/Q fragments: lane holds X[row = f*32 + c][d = kd*16 + b5*8 + j], rows clamped
  bf16x8 kf[2][2], qf[2][2];
#pragma unroll
  for (int f = 0; f < 2; ++f) {
    int row = f * 32 + c; if (row > 48) row = 48;
#pragma unroll
    for (int kd = 0; kd < 2; ++kd) {
      kf[f][kd] = *reinterpret_cast<const bf16x8*>(&K[base + row * 32 + kd * 16 + b5 * 8]);
      qf[f][kd] = *reinterpret_cast<const bf16x8*>(&Q[base + row * 32 + kd * 16 + b5 * 8]);
    }
  }

  const float scale = 0.17677669529663689f;   // 32^-0.5
  const float* bm = bmT + ((size_t)h * 64 + w) * 2401;

#pragma unroll
  for (int fn = 0; fn < 2; ++fn) {
    // swapped QK^T: S[key][q], C layout col=lane&31=q, row=(r&3)+8*(r>>2)+4*b5=key
    f32x16 s0 = {}, s1 = {};
    __builtin_amdgcn_s_setprio(1);
    s0 = MFMA32(kf[0][0], qf[fn][0], s0);
    s0 = MFMA32(kf[0][1], qf[fn][1], s0);
    s1 = MFMA32(kf[1][0], qf[fn][0], s1);
    s1 = MFMA32(kf[1][1], qf[fn][1], s1);
    __builtin_amdgcn_s_setprio(0);

    int q = fn * 32 + c;
    int qc = q > 48 ? 48 : q;

    // softmax without max-subtract: e = exp(score); |score| <= ~6 in f32-safe range
    float vals[32];
    float sum = 0.f;
#pragma unroll
    for (int fm = 0; fm < 2; ++fm) {
#pragma unroll
      for (int r = 0; r < 16; ++r) {
        int key = fm * 32 + (r & 3) + 8 * (r >> 2) + 4 * b5;
        float sv = fm ? s1[r] : s0[r];
        float e;
        if (key < 49) {
          e = __expf(fmaf(sv, scale, bm[key * 49 + qc]));
        } else {
          e = 0.f;
        }
        vals[fm * 16 + r] = e;
        sum += e;
      }
    }
    sum += __shfl_xor(sum, 32);
    float inv = 1.f / sum;

    // PV: build P A-frags in-register (cvt pack + permlane32_swap), MFMA with LDS V
    f32x16 o = {};
#pragma unroll
    for (int kk = 0; kk < 4; ++kk) {
      int ib = (kk >> 1) * 16 + 8 * (kk & 1);
      union { bf16 hh[2]; u32 u; } cv;
      u32 A0, A1, B0, B1;
      cv.hh[0] = (bf16)(vals[ib + 0] * inv); cv.hh[1] = (bf16)(vals[ib + 1] * inv); A0 = cv.u;
      cv.hh[0] = (bf16)(vals[ib + 2] * inv); cv.hh[1] = (bf16)(vals[ib + 3] * inv); A1 = cv.u;
      cv.hh[0] = (bf16)(vals[ib + 4] * inv); cv.hh[1] = (bf16)(vals[ib + 5] * inv); B0 = cv.u;
      cv.hh[0] = (bf16)(vals[ib + 6] * inv); cv.hh[1] = (bf16)(vals[ib + 7] * inv); B1 = cv.u;
      i32x2 sw0 = __builtin_amdgcn_permlane32_swap((int)A0, (int)B0, false, false);
      i32x2 sw1 = __builtin_amdgcn_permlane32_swap((int)A1, (int)B1, false, false);
      union { u32 d[4]; bf16x8 v8; } pa;
      pa.d[0] = (u32)sw0[0]; pa.d[1] = (u32)sw1[0];
      pa.d[2] = (u32)sw0[1]; pa.d[3] = (u32)sw1[1];
      bf16x8 vf = *reinterpret_cast<const bf16x8*>(&vl[c * 72 + kk * 16 + b5 * 8]);
      __builtin_amdgcn_s_setprio(1);
      o = MFMA32(pa.v8, vf, o);
      __builtin_amdgcn_s_setprio(0);
    }

    // store O: row q = fn*32 + (r&3)+8*(r>>2)+4*b5, col d = c
#pragma unroll
    for (int r = 0; r < 16; ++r) {
      int qrow = fn * 32 + (r & 3) + 8 * (r >> 2) + 4 * b5;
      if (qrow < 49)
        H[((size_t)b * 49 + qrow) * 384 + h * 32 + c] = (bf16)o[r];
    }
  }
}

extern "C" void kernel_launch(void* const* d_in, const int* in_sizes, int n_in,
                              void* d_out, int out_size, void* d_ws, size_t ws_size,
                              hipStream_t stream) {
  const float* x     = (const float*)d_in[0];
  const float* mask  = (const float*)d_in[1];
  const float* qkvw  = (const float*)d_in[2];
  const float* qkvb  = (const float*)d_in[3];
  const float* btab  = (const float*)d_in[4];
  const float* projw = (const float*)d_in[5];
  const float* projb = (const float*)d_in[6];
  const int*   rel   = (const int*)d_in[7];
  float* out = (float*)d_out;

  const size_t NB  = 154140672;   // one [200704][384] bf16 buffer (bytes)
  char* ws = (char*)d_ws;
  // ws layout: xb/h [0,NB) | v [NB,2NB) | wqkv (+884736) | wproj (+294912) | bmT (7.4MB)
  bf16*  xb    = (bf16*)ws;
  bf16*  vb    = (bf16*)(ws + NB);
  bf16*  wqkv  = (bf16*)(ws + 2 * NB);
  bf16*  wproj = (bf16*)(ws + 2 * NB + 884736);
  float* bmT   = (float*)(ws + 2 * NB + 884736 + 294912);
  // q,k packed (p,49,32) live in d_out scratch (2*154,140,672 B exactly)
  bf16* qb = (bf16*)d_out;
  bf16* kb = qb + NB / 2;

  k_convert<<<2048, 256, 0, stream>>>((const float4*)x, (bf16x4*)xb, (int)(NB / 8));
  k_prep<<<7779, 256, 0, stream>>>(qkvw, projw, btab, rel, mask, wqkv, wproj, bmT);

  k_gemm<0><<<dim3(9, MROWS / 128), 256, 0, stream>>>(xb, wqkv, qkvb, qb, kb, vb, nullptr);
  k_attn<<<(NWINB * NHEADS) / 4, 256, 0, stream>>>(qb, kb, vb, bmT, xb);
  k_gemm<1><<<dim3(3, MROWS / 128), 256, 0, stream>>>(xb, wproj, projb, nullptr, nullptr, nullptr, out);
}